// Round 8
// baseline (821.852 us; speedup 1.0000x reference)
//
#include <hip/hip_runtime.h>
#include <hip/hip_bf16.h>

#define IN_DIM 128
#define HID 64
#define NEG_SLOPE 0.01f

typedef __attribute__((ext_vector_type(8))) short short8;
typedef __attribute__((ext_vector_type(4))) short short4v;
typedef __attribute__((ext_vector_type(4))) float f32x4;
typedef unsigned short ushort_t;
typedef unsigned int uint_t;

__device__ __forceinline__ float fsig(float x) { return 1.f / (1.f + __expf(-x)); }
__device__ __forceinline__ float ftanh(float x) { return 1.f - 2.f / (__expf(2.f * x) + 1.f); }

__device__ __forceinline__ ushort_t f2bf(float f) {
    uint_t u = __float_as_uint(f);
    uint_t r = u + 0x7fffu + ((u >> 16) & 1u);  // round-to-nearest-even
    return (ushort_t)(r >> 16);
}
__device__ __forceinline__ float bf2f(ushort_t s) { return __uint_as_float(((uint_t)s) << 16); }
__device__ __forceinline__ float bf2f_s(short s) { return bf2f((ushort_t)s); }

// device-scope grid barrier; grid is sized to be fully co-resident (occupancy query)
__device__ __forceinline__ void gbar(int* bar, int idx, int nb) {
    __syncthreads();
    if (threadIdx.x == 0) {
        __threadfence();                       // release: publish our stores
        atomicAdd(&bar[idx], 1);
        while (atomicAdd(&bar[idx], 0) < nb) __builtin_amdgcn_s_sleep(2);
        __threadfence();                       // acquire: see others' stores
    }
    __syncthreads();
}

// ---- one persistent kernel, 4 phases --------------------------------------
__global__ __launch_bounds__(256, 3) void mega_kernel(
    const int* __restrict__ src, const int* __restrict__ dst, const float* __restrict__ ew,
    const float* __restrict__ x, const float* __restrict__ h,
    const float* __restrict__ Wx, const float* __restrict__ Wh,
    const float* __restrict__ c_in,
    const float* __restrict__ bx, const float* __restrict__ bh,
    const float* __restrict__ wc, const float* __restrict__ bg,
    const float* __restrict__ Whead, const float* __restrict__ bhead,
    float* __restrict__ deg, int* __restrict__ cnt, int* __restrict__ rank_,
    int* __restrict__ rowptr, int* __restrict__ bsum, int2* __restrict__ eprm,
    uint_t* __restrict__ xb_u, uint_t* __restrict__ hb_u, ushort_t* __restrict__ Wp,
    int* __restrict__ bar, float* __restrict__ out, int E, int N) {

    __shared__ ushort_t TxL[4][16][136];  // 17.4 KB, wave-private gather results
    __shared__ ushort_t ThL[4][16][72];   //  9.2 KB
    __shared__ int sdata[256];
    __shared__ int bsumpref[64];

    const ushort_t* xb = (const ushort_t*)xb_u;
    const ushort_t* hb = (const ushort_t*)hb_u;
    int tid = threadIdx.x;
    int gtid = blockIdx.x * 256 + tid;
    int T = gridDim.x * 256;
    int nGrid = gridDim.x;

    // ---------------- P0: deg/cnt atomics + rank, cvt, pack ----------------
    for (int e = gtid; e < E; e += T) {
        atomicAdd(&deg[src[e]], ew[e]);
        rank_[e] = atomicAdd(&cnt[dst[e]], 1);
    }
    int ncvt = N * 96, nx = N * 64;
    for (int i = gtid; i < ncvt; i += T) {
        if (i < nx) {
            float2 v = ((const float2*)x)[i];
            xb_u[i] = (uint_t)f2bf(v.x) | ((uint_t)f2bf(v.y) << 16);
        } else {
            int j = i - nx;
            float2 v = ((const float2*)h)[j];
            hb_u[j] = (uint_t)f2bf(v.x) | ((uint_t)f2bf(v.y) << 16);
        }
    }
    // Wp[((ks*16+ct)*64+lane)*8+j] = W[k=ks*32+(lane>>4)*8+j][colg=ct*16+(lane&15)]
    for (int idx = gtid; idx < 384 * 256; idx += T) {
        int j = idx & 7;
        int tmp = idx >> 3;
        int lane = tmp & 63;
        int t2 = tmp >> 6;
        int ct = t2 & 15;
        int ks = t2 >> 4;
        int k = ks * 32 + (lane >> 4) * 8 + j;
        int colg = ct * 16 + (lane & 15);
        int g = colg >> 6, hd = colg & 63;
        float v;
        if (k < 128)      v = Wx[((g * 2 + 0) * 128 + k) * 64 + hd];
        else if (k < 192) v = Wh[((g * 2 + 0) * 64 + (k - 128)) * 64 + hd];
        else if (k < 320) v = Wx[((g * 2 + 1) * 128 + (k - 192)) * 64 + hd];
        else              v = Wh[((g * 2 + 1) * 64 + (k - 320)) * 64 + hd];
        Wp[idx] = f2bf(v);
    }
    gbar(bar, 0, nGrid);

    // ---------------- P1: per-chunk exclusive scan of cnt ------------------
    int nScan = N + 1;
    int nChunk = (nScan + 1023) >> 10;   // 49 for N=50000
    if ((int)blockIdx.x < nChunk) {
        int b = blockIdx.x;
        int base = b * 1024 + tid * 4;
        int v[4];
        int tsum = 0;
#pragma unroll
        for (int j = 0; j < 4; ++j) {
            int idx = base + j;
            v[j] = (idx < N) ? cnt[idx] : 0;
            tsum += v[j];
        }
        sdata[tid] = tsum;
        __syncthreads();
        for (int off = 1; off < 256; off <<= 1) {
            int tmp = (tid >= off) ? sdata[tid - off] : 0;
            __syncthreads();
            sdata[tid] += tmp;
            __syncthreads();
        }
        if (tid == 255) bsum[b] = sdata[255];
        int run = sdata[tid] - tsum;
#pragma unroll
        for (int j = 0; j < 4; ++j) {
            int idx = base + j;
            if (idx < nScan) rowptr[idx] = run;  // chunk-local exclusive prefix
            run += v[j];
        }
    }
    gbar(bar, 1, nGrid);

    // every block: exclusive prefix of bsum into LDS (nChunk <= 64)
    if (tid < 64) {
        int v0 = (tid < nChunk) ? bsum[tid] : 0;
        int v = v0;
#pragma unroll
        for (int off = 1; off < 64; off <<= 1) {
            int t = __shfl_up(v, off);
            if (tid >= off) v += t;
        }
        bsumpref[tid] = v - v0;
    }
    __syncthreads();

    // ---------------- P2: fill packed CSR (atomic-free) --------------------
    for (int e = gtid; e < E; e += T) {
        int d = dst[e];
        int s = src[e];
        float ds = deg[s], dd = deg[d];
        float dis = ds > 0.f ? rsqrtf(ds) : 0.f;
        float did = dd > 0.f ? rsqrtf(dd) : 0.f;
        float nrm = -dis * ew[e] * did;
        int pos = rowptr[d] + bsumpref[d >> 10] + rank_[e];
        eprm[pos] = make_int2(s, __float_as_int(nrm));
    }
    gbar(bar, 2, nGrid);

    // ---------------- P3: per-64-row tile: gather->LDS + MFMA + LSTM -------
    int nTiles = (N + 63) >> 6;
    int lane = tid & 63;
    int wave = tid >> 6;
    int grp = lane >> 4, l16 = lane & 15;
    int quad = lane >> 4, m = lane & 15;

    for (int tile = blockIdx.x; tile < nTiles; tile += nGrid) {
        int row0 = (tile * 4 + wave) * 16;

        // gather phase: 16 lanes per node, 4 nodes concurrent per wave
        for (int ni = 0; ni < 4; ++ni) {
            int nl = ni * 4 + grp;
            int node = row0 + nl;
            int p = 0, end = 0;
            if (node < N) {
                p = rowptr[node] + bsumpref[node >> 10];
                end = rowptr[node + 1] + bsumpref[(node + 1) >> 10];
            }
            float ax[8] = {0.f, 0.f, 0.f, 0.f, 0.f, 0.f, 0.f, 0.f};
            float ah[4] = {0.f, 0.f, 0.f, 0.f};

            for (int base = p; base < end; base += 16) {
                int idx = base + l16;
                int2 pr = (idx < end) ? eprm[idx] : make_int2(0, 0);
                int sv = pr.x;
                float wv = __int_as_float(pr.y);
                int mcount = end - base; if (mcount > 16) mcount = 16;
                int sl0 = grp * 16;
                int j = 0;
                for (; j + 4 <= mcount; j += 4) {
                    int s0 = __shfl(sv, sl0 + j + 0), s1 = __shfl(sv, sl0 + j + 1);
                    int s2 = __shfl(sv, sl0 + j + 2), s3 = __shfl(sv, sl0 + j + 3);
                    float w0 = __shfl(wv, sl0 + j + 0), w1 = __shfl(wv, sl0 + j + 1);
                    float w2 = __shfl(wv, sl0 + j + 2), w3 = __shfl(wv, sl0 + j + 3);
                    short8 xv0 = *(const short8*)(xb + (size_t)s0 * 128 + l16 * 8);
                    short8 xv1 = *(const short8*)(xb + (size_t)s1 * 128 + l16 * 8);
                    short8 xv2 = *(const short8*)(xb + (size_t)s2 * 128 + l16 * 8);
                    short8 xv3 = *(const short8*)(xb + (size_t)s3 * 128 + l16 * 8);
                    short4v hv0 = *(const short4v*)(hb + (size_t)s0 * 64 + l16 * 4);
                    short4v hv1 = *(const short4v*)(hb + (size_t)s1 * 64 + l16 * 4);
                    short4v hv2 = *(const short4v*)(hb + (size_t)s2 * 64 + l16 * 4);
                    short4v hv3 = *(const short4v*)(hb + (size_t)s3 * 64 + l16 * 4);
#pragma unroll
                    for (int i = 0; i < 8; ++i)
                        ax[i] += w0 * bf2f_s(xv0[i]) + w1 * bf2f_s(xv1[i])
                               + w2 * bf2f_s(xv2[i]) + w3 * bf2f_s(xv3[i]);
#pragma unroll
                    for (int i = 0; i < 4; ++i)
                        ah[i] += w0 * bf2f_s(hv0[i]) + w1 * bf2f_s(hv1[i])
                               + w2 * bf2f_s(hv2[i]) + w3 * bf2f_s(hv3[i]);
                }
                for (; j < mcount; ++j) {
                    int s0 = __shfl(sv, sl0 + j);
                    float w0 = __shfl(wv, sl0 + j);
                    short8 xv0 = *(const short8*)(xb + (size_t)s0 * 128 + l16 * 8);
                    short4v hv0 = *(const short4v*)(hb + (size_t)s0 * 64 + l16 * 4);
#pragma unroll
                    for (int i = 0; i < 8; ++i) ax[i] += w0 * bf2f_s(xv0[i]);
#pragma unroll
                    for (int i = 0; i < 4; ++i) ah[i] += w0 * bf2f_s(hv0[i]);
                }
            }
            short8 tx;
#pragma unroll
            for (int i = 0; i < 8; ++i) tx[i] = (short)f2bf(ax[i]);
            *(short8*)&TxL[wave][nl][l16 * 8] = tx;
            short4v th;
#pragma unroll
            for (int i = 0; i < 4; ++i) th[i] = (short)f2bf(ah[i]);
            *(short4v*)&ThL[wave][nl][l16 * 4] = th;
        }
        // no __syncthreads: each wave reads only its own LDS region

        // MFMA phase
        int ar = row0 + m; if (ar >= N) ar = N - 1;
        int ko = quad * 8;

        f32x4 acc[16];
#pragma unroll
        for (int ct = 0; ct < 16; ++ct) {
            int g = ct >> 2, hd = (ct & 3) * 16 + m;
            float b = bx[g * 64 + hd] + bh[g * 64 + hd];
            f32x4 bb = {b, b, b, b};
            acc[ct] = bb;
        }

        const short8* Wp8 = (const short8*)Wp;
#pragma unroll
        for (int ks = 0; ks < 12; ++ks) {
            short8 af;
            if (ks < 4)       af = *(const short8*)(xb + (size_t)ar * 128 + ks * 32 + ko);
            else if (ks < 6)  af = *(const short8*)(hb + (size_t)ar * 64 + (ks - 4) * 32 + ko);
            else if (ks < 10) af = *(const short8*)&TxL[wave][m][(ks - 6) * 32 + ko];
            else              af = *(const short8*)&ThL[wave][m][(ks - 10) * 32 + ko];
#pragma unroll
            for (int ct = 0; ct < 16; ++ct) {
                short8 bf = Wp8[(ks * 16 + ct) * 64 + lane];
                acc[ct] = __builtin_amdgcn_mfma_f32_16x16x32_bf16(af, bf, acc[ct], 0, 0, 0);
            }
        }

        float hp[4] = {0.f, 0.f, 0.f, 0.f};
        float bhv = bhead[0];
#pragma unroll
        for (int hs = 0; hs < 4; ++hs) {
            int hd = hs * 16 + m;
            float wc0 = wc[hd], wc1 = wc[64 + hd], wc2 = wc[128 + hd];
            float bg0 = bg[hd], bg1 = bg[64 + hd], bg2 = bg[128 + hd], bg3 = bg[192 + hd];
            float wh = Whead[hd];
#pragma unroll
            for (int reg = 0; reg < 4; ++reg) {
                int n = row0 + quad * 4 + reg;
                if (n < N) {
                    float c_old = c_in[(size_t)n * 64 + hd];
                    float zi = acc[0 * 4 + hs][reg];
                    float zf = acc[1 * 4 + hs][reg];
                    float zg = acc[2 * 4 + hs][reg];
                    float zo = acc[3 * 4 + hs][reg];
                    float ii = fsig(zi + wc0 * c_old + bg0);
                    float ff = fsig(zf + wc1 * c_old + bg1);
                    float gg = ftanh(zg + bg2);
                    float cn = ff * c_old + ii * gg;
                    float oo = fsig(zo + wc2 * cn + bg3);
                    float hn = oo * ftanh(cn);
                    out[N + (size_t)n * 64 + hd] = hn;
                    out[N + (size_t)N * 64 + (size_t)n * 64 + hd] = cn;
                    float lr = hn > 0.f ? hn : NEG_SLOPE * hn;
                    hp[reg] += lr * wh;
                }
            }
        }
#pragma unroll
        for (int reg = 0; reg < 4; ++reg) {
            float v0 = hp[reg];
#pragma unroll
            for (int mask = 1; mask < 16; mask <<= 1) v0 += __shfl_xor(v0, mask);
            if (m == 0) {
                int n0_ = row0 + quad * 4 + reg;
                if (n0_ < N) out[n0_] = v0 + bhv;
            }
        }
    }
}

extern "C" void kernel_launch(void* const* d_in, const int* in_sizes, int n_in,
                              void* d_out, int out_size, void* d_ws, size_t ws_size,
                              hipStream_t stream) {
    const float* x = (const float*)d_in[0];
    const int* ei = (const int*)d_in[1];
    const float* ew = (const float*)d_in[2];
    const float* h = (const float*)d_in[3];
    const float* c = (const float*)d_in[4];
    const float* Wx = (const float*)d_in[5];
    const float* bx = (const float*)d_in[6];
    const float* Wh = (const float*)d_in[7];
    const float* bh = (const float*)d_in[8];
    const float* wc = (const float*)d_in[9];
    const float* bg = (const float*)d_in[10];
    const float* Whead = (const float*)d_in[11];
    const float* bhead = (const float*)d_in[12];

    int N = in_sizes[0] / IN_DIM;  // 50000
    int E = in_sizes[1] / 2;       // 800000
    const int* src = ei;
    const int* dst = ei + E;

    char* wp = (char*)d_ws;
    auto alloc = [&](size_t bytes) {
        char* p = wp;
        wp += (bytes + 255) & ~(size_t)255;
        return p;
    };
    int* bar = (int*)alloc((size_t)(64 + 2 * N) * 4);  // bar | deg | cnt, one memset
    float* deg = (float*)(bar + 64);
    int* cnt = (int*)(deg + N);
    int* rank_ = (int*)alloc((size_t)E * 4);
    int* rowptr = (int*)alloc((size_t)(N + 2) * 4);
    int* bsum = (int*)alloc(64 * 4);
    int2* eprm = (int2*)alloc((size_t)E * 8);
    ushort_t* xb = (ushort_t*)alloc((size_t)N * 128 * 2);
    ushort_t* hb = (ushort_t*)alloc((size_t)N * 64 * 2);
    ushort_t* Wp = (ushort_t*)alloc((size_t)384 * 256 * 2);

    hipMemsetAsync(bar, 0, (size_t)(64 + 2 * N) * sizeof(int), stream);

    // grid sized to guaranteed co-residency (spin barrier safety)
    int occ = 0;
    hipOccupancyMaxActiveBlocksPerMultiprocessor(&occ, mega_kernel, 256, 0);
    if (occ < 1) occ = 1;
    int grid = occ * 256;   // 256 CUs on MI355X

    mega_kernel<<<grid, 256, 0, stream>>>(src, dst, ew, x, h, Wx, Wh, c,
                                          bx, bh, wc, bg, Whead, bhead,
                                          deg, cnt, rank_, rowptr, bsum, eprm,
                                          (uint_t*)xb, (uint_t*)hb, Wp,
                                          bar, (float*)d_out, E, N);
}

// Round 9
// 293.138 us; speedup vs baseline: 2.8036x; 2.8036x over previous
//
#include <hip/hip_runtime.h>
#include <hip/hip_bf16.h>

#define IN_DIM 128
#define HID 64
#define NEG_SLOPE 0.01f

typedef __attribute__((ext_vector_type(8))) short short8;
typedef __attribute__((ext_vector_type(4))) short short4v;
typedef __attribute__((ext_vector_type(4))) float f32x4;
typedef unsigned short ushort_t;
typedef unsigned int uint_t;

__device__ __forceinline__ float fsig(float x) { return 1.f / (1.f + __expf(-x)); }
__device__ __forceinline__ float ftanh(float x) { return 1.f - 2.f / (__expf(2.f * x) + 1.f); }

__device__ __forceinline__ ushort_t f2bf(float f) {
    uint_t u = __float_as_uint(f);
    uint_t r = u + 0x7fffu + ((u >> 16) & 1u);  // round-to-nearest-even
    return (ushort_t)(r >> 16);
}
__device__ __forceinline__ float bf2f(ushort_t s) { return __uint_as_float(((uint_t)s) << 16); }
__device__ __forceinline__ float bf2f_s(short s) { return bf2f((ushort_t)s); }

// ---- K1: deg/cnt atomics + rank + bf16 convert + weight pack ----------------
// Atomic-bound threads are ~98% idle; the streaming work rides free (R6-proven).
__global__ __launch_bounds__(256) void prep_kernel(
    const int* __restrict__ src, const int* __restrict__ dst, const float* __restrict__ ew,
    const float* __restrict__ x, const float* __restrict__ h,
    const float* __restrict__ Wx, const float* __restrict__ Wh,
    float* __restrict__ deg, int* __restrict__ cnt, int* __restrict__ rank_,
    uint_t* __restrict__ xb_u, uint_t* __restrict__ hb_u, ushort_t* __restrict__ Wp,
    int E, int N) {
    int tid = blockIdx.x * 256 + threadIdx.x;
    int T = gridDim.x * 256;

    if (tid < E) {
        atomicAdd(&deg[src[tid]], ew[tid]);
        rank_[tid] = atomicAdd(&cnt[dst[tid]], 1);   // rank within dst bucket
    }

    // cvt: x pairs [0, N*64), h pairs [N*64, N*96)
    int ncvt = N * 96;
    int nx = N * 64;
    for (int i = tid; i < ncvt; i += T) {
        if (i < nx) {
            float2 v = ((const float2*)x)[i];
            xb_u[i] = (uint_t)f2bf(v.x) | ((uint_t)f2bf(v.y) << 16);
        } else {
            int j = i - nx;
            float2 v = ((const float2*)h)[j];
            hb_u[j] = (uint_t)f2bf(v.x) | ((uint_t)f2bf(v.y) << 16);
        }
    }

    // pack weights into MFMA B-fragment layout, [ks][ct] contiguous:
    // Wp[((ks*16+ct)*64+lane)*8+j] = W[k=ks*32+(lane>>4)*8+j][colg=ct*16+(lane&15)]
    for (int idx = tid; idx < 384 * 256; idx += T) {
        int j = idx & 7;
        int tmp = idx >> 3;
        int lane = tmp & 63;
        int t2 = tmp >> 6;
        int ct = t2 & 15;
        int ks = t2 >> 4;
        int k = ks * 32 + (lane >> 4) * 8 + j;
        int colg = ct * 16 + (lane & 15);
        int g = colg >> 6, hd = colg & 63;
        float v;
        if (k < 128)      v = Wx[((g * 2 + 0) * 128 + k) * 64 + hd];
        else if (k < 192) v = Wh[((g * 2 + 0) * 64 + (k - 128)) * 64 + hd];
        else if (k < 320) v = Wx[((g * 2 + 1) * 128 + (k - 192)) * 64 + hd];
        else              v = Wh[((g * 2 + 1) * 64 + (k - 320)) * 64 + hd];
        Wp[idx] = f2bf(v);
    }
}

// ---- K2: scan1: per-1024-chunk exclusive scan of cnt + chunk sums -----------
__global__ __launch_bounds__(256) void scan1_kernel(const int* __restrict__ cnt,
                                                    int* __restrict__ rowptr,
                                                    int* __restrict__ bsum, int n, int N) {
    __shared__ int sdata[256];
    int b = blockIdx.x, t = threadIdx.x;
    int base = b * 1024 + t * 4;
    int v[4];
    int tsum = 0;
#pragma unroll
    for (int j = 0; j < 4; ++j) {
        int idx = base + j;
        v[j] = (idx < N) ? cnt[idx] : 0;
        tsum += v[j];
    }
    sdata[t] = tsum;
    __syncthreads();
    for (int off = 1; off < 256; off <<= 1) {
        int tmp = (t >= off) ? sdata[t - off] : 0;
        __syncthreads();
        sdata[t] += tmp;
        __syncthreads();
    }
    if (t == 255) bsum[b] = sdata[255];
    int run = sdata[t] - tsum;
#pragma unroll
    for (int j = 0; j < 4; ++j) {
        int idx = base + j;
        if (idx < n) rowptr[idx] = run;   // chunk-local exclusive prefix
        run += v[j];
    }
}

// ---- K3: fill packed CSR (atomic-free); chunk offsets via in-LDS prefix -----
__global__ __launch_bounds__(256) void fill_kernel(
    const int* __restrict__ src, const int* __restrict__ dst, const float* __restrict__ ew,
    const float* __restrict__ deg, const int* __restrict__ rowptr,
    const int* __restrict__ rank_, const int* __restrict__ bsum, int nChunk,
    int2* __restrict__ eprm, int E) {
    __shared__ int bsumpref[64];
    int t = threadIdx.x;
    if (t < 64) {
        int v0 = (t < nChunk) ? bsum[t] : 0;
        int v = v0;
#pragma unroll
        for (int off = 1; off < 64; off <<= 1) {
            int tt = __shfl_up(v, off);
            if (t >= off) v += tt;
        }
        bsumpref[t] = v - v0;   // exclusive
    }
    __syncthreads();
    int e = blockIdx.x * 256 + t;
    if (e < E) {
        int d = dst[e];
        int s = src[e];
        float ds = deg[s], dd = deg[d];
        float dis = ds > 0.f ? rsqrtf(ds) : 0.f;
        float did = dd > 0.f ? rsqrtf(dd) : 0.f;
        float nrm = -dis * ew[e] * did;
        int pos = rowptr[d] + bsumpref[d >> 10] + rank_[e];
        eprm[pos] = make_int2(s, __float_as_int(nrm));
    }
}

// ---- K4: gather (to LDS) + MFMA GEMM + LSTM gates + head --------------------
// Block = 4 waves = 64 rows. Wave gathers Tx/Th for its 16 rows into private
// LDS (16 lanes/node, 4 nodes in flight), then MFMA phase reads Tx/Th A-frags
// from LDS, x/h A-frags from global, B-frags from L2-resident Wp.
__global__ __launch_bounds__(256, 4) void gather_mfma(
    const int* __restrict__ rowptr, const int* __restrict__ bsum, int nChunk,
    const int2* __restrict__ eprm,
    const ushort_t* __restrict__ xb, const ushort_t* __restrict__ hb,
    const float* __restrict__ c_in, const ushort_t* __restrict__ Wp,
    const float* __restrict__ bx, const float* __restrict__ bh,
    const float* __restrict__ wc, const float* __restrict__ bg,
    const float* __restrict__ Whead, const float* __restrict__ bhead,
    float* __restrict__ out, int N) {
    __shared__ ushort_t TxL[4][16][136];  // 17.4 KB; pad 8 shorts -> 2-way (free)
    __shared__ ushort_t ThL[4][16][72];   //  9.2 KB
    __shared__ int bsumpref[64];
    int tid = threadIdx.x;
    int lane = tid & 63;
    int wave = tid >> 6;
    int grp = lane >> 4, l16 = lane & 15;
    int row0 = (blockIdx.x * 4 + wave) * 16;

    if (tid < 64) {
        int v0 = (tid < nChunk) ? bsum[tid] : 0;
        int v = v0;
#pragma unroll
        for (int off = 1; off < 64; off <<= 1) {
            int tt = __shfl_up(v, off);
            if (tid >= off) v += tt;
        }
        bsumpref[tid] = v - v0;
    }
    __syncthreads();

    // ---------------- gather phase ----------------
    for (int ni = 0; ni < 4; ++ni) {
        int nl = ni * 4 + grp;            // node-local index 0..15
        int node = row0 + nl;
        int p = 0, end = 0;
        if (node < N) {
            p = rowptr[node] + bsumpref[node >> 10];
            end = rowptr[node + 1] + bsumpref[(node + 1) >> 10];
        }
        float ax[8] = {0.f, 0.f, 0.f, 0.f, 0.f, 0.f, 0.f, 0.f};
        float ah[4] = {0.f, 0.f, 0.f, 0.f};

        for (int base = p; base < end; base += 16) {
            int idx = base + l16;
            int2 pr = (idx < end) ? eprm[idx] : make_int2(0, 0);
            int sv = pr.x;
            float wv = __int_as_float(pr.y);
            int mcount = end - base; if (mcount > 16) mcount = 16;
            int sl0 = grp * 16;
            int j = 0;
            for (; j + 4 <= mcount; j += 4) {
                int s0 = __shfl(sv, sl0 + j + 0), s1 = __shfl(sv, sl0 + j + 1);
                int s2 = __shfl(sv, sl0 + j + 2), s3 = __shfl(sv, sl0 + j + 3);
                float w0 = __shfl(wv, sl0 + j + 0), w1 = __shfl(wv, sl0 + j + 1);
                float w2 = __shfl(wv, sl0 + j + 2), w3 = __shfl(wv, sl0 + j + 3);
                short8 xv0 = *(const short8*)(xb + (size_t)s0 * 128 + l16 * 8);
                short8 xv1 = *(const short8*)(xb + (size_t)s1 * 128 + l16 * 8);
                short8 xv2 = *(const short8*)(xb + (size_t)s2 * 128 + l16 * 8);
                short8 xv3 = *(const short8*)(xb + (size_t)s3 * 128 + l16 * 8);
                short4v hv0 = *(const short4v*)(hb + (size_t)s0 * 64 + l16 * 4);
                short4v hv1 = *(const short4v*)(hb + (size_t)s1 * 64 + l16 * 4);
                short4v hv2 = *(const short4v*)(hb + (size_t)s2 * 64 + l16 * 4);
                short4v hv3 = *(const short4v*)(hb + (size_t)s3 * 64 + l16 * 4);
#pragma unroll
                for (int i = 0; i < 8; ++i)
                    ax[i] += w0 * bf2f_s(xv0[i]) + w1 * bf2f_s(xv1[i])
                           + w2 * bf2f_s(xv2[i]) + w3 * bf2f_s(xv3[i]);
#pragma unroll
                for (int i = 0; i < 4; ++i)
                    ah[i] += w0 * bf2f_s(hv0[i]) + w1 * bf2f_s(hv1[i])
                           + w2 * bf2f_s(hv2[i]) + w3 * bf2f_s(hv3[i]);
            }
            for (; j < mcount; ++j) {
                int s0 = __shfl(sv, sl0 + j);
                float w0 = __shfl(wv, sl0 + j);
                short8 xv0 = *(const short8*)(xb + (size_t)s0 * 128 + l16 * 8);
                short4v hv0 = *(const short4v*)(hb + (size_t)s0 * 64 + l16 * 4);
#pragma unroll
                for (int i = 0; i < 8; ++i) ax[i] += w0 * bf2f_s(xv0[i]);
#pragma unroll
                for (int i = 0; i < 4; ++i) ah[i] += w0 * bf2f_s(hv0[i]);
            }
        }
        short8 tx;
#pragma unroll
        for (int i = 0; i < 8; ++i) tx[i] = (short)f2bf(ax[i]);
        *(short8*)&TxL[wave][nl][l16 * 8] = tx;
        short4v th;
#pragma unroll
        for (int i = 0; i < 4; ++i) th[i] = (short)f2bf(ah[i]);
        *(short4v*)&ThL[wave][nl][l16 * 4] = th;
    }
    // no __syncthreads: each wave reads only its own LDS region

    // ---------------- MFMA phase ----------------
    int quad = lane >> 4, m = lane & 15;
    int ar = row0 + m; if (ar >= N) ar = N - 1;
    int ko = quad * 8;

    f32x4 acc[16];
#pragma unroll
    for (int ct = 0; ct < 16; ++ct) {
        int g = ct >> 2, hd = (ct & 3) * 16 + m;
        float b = bx[g * 64 + hd] + bh[g * 64 + hd];
        f32x4 bb = {b, b, b, b};
        acc[ct] = bb;
    }

    const short8* Wp8 = (const short8*)Wp;
#pragma unroll
    for (int ks = 0; ks < 12; ++ks) {
        short8 af;
        if (ks < 4)       af = *(const short8*)(xb + (size_t)ar * 128 + ks * 32 + ko);
        else if (ks < 6)  af = *(const short8*)(hb + (size_t)ar * 64 + (ks - 4) * 32 + ko);
        else if (ks < 10) af = *(const short8*)&TxL[wave][m][(ks - 6) * 32 + ko];
        else              af = *(const short8*)&ThL[wave][m][(ks - 10) * 32 + ko];
#pragma unroll
        for (int ct = 0; ct < 16; ++ct) {
            short8 bf = Wp8[(ks * 16 + ct) * 64 + lane];
            acc[ct] = __builtin_amdgcn_mfma_f32_16x16x32_bf16(af, bf, acc[ct], 0, 0, 0);
        }
    }

    float hp[4] = {0.f, 0.f, 0.f, 0.f};
    float bhv = bhead[0];

#pragma unroll
    for (int hs = 0; hs < 4; ++hs) {
        int hd = hs * 16 + m;
        float wc0 = wc[hd], wc1 = wc[64 + hd], wc2 = wc[128 + hd];
        float bg0 = bg[hd], bg1 = bg[64 + hd], bg2 = bg[128 + hd], bg3 = bg[192 + hd];
        float wh = Whead[hd];
#pragma unroll
        for (int reg = 0; reg < 4; ++reg) {
            int n = row0 + quad * 4 + reg;
            if (n < N) {
                float c_old = c_in[(size_t)n * 64 + hd];
                float zi = acc[0 * 4 + hs][reg];
                float zf = acc[1 * 4 + hs][reg];
                float zg = acc[2 * 4 + hs][reg];
                float zo = acc[3 * 4 + hs][reg];
                float ii = fsig(zi + wc0 * c_old + bg0);
                float ff = fsig(zf + wc1 * c_old + bg1);
                float gg = ftanh(zg + bg2);
                float cn = ff * c_old + ii * gg;
                float oo = fsig(zo + wc2 * cn + bg3);
                float hn = oo * ftanh(cn);
                out[N + (size_t)n * 64 + hd] = hn;
                out[N + (size_t)N * 64 + (size_t)n * 64 + hd] = cn;
                float lr = hn > 0.f ? hn : NEG_SLOPE * hn;
                hp[reg] += lr * wh;
            }
        }
    }
#pragma unroll
    for (int reg = 0; reg < 4; ++reg) {
        float v0 = hp[reg];
#pragma unroll
        for (int mask = 1; mask < 16; mask <<= 1) v0 += __shfl_xor(v0, mask);
        if (m == 0) {
            int n0_ = row0 + quad * 4 + reg;
            if (n0_ < N) out[n0_] = v0 + bhv;
        }
    }
}

extern "C" void kernel_launch(void* const* d_in, const int* in_sizes, int n_in,
                              void* d_out, int out_size, void* d_ws, size_t ws_size,
                              hipStream_t stream) {
    const float* x = (const float*)d_in[0];
    const int* ei = (const int*)d_in[1];
    const float* ew = (const float*)d_in[2];
    const float* h = (const float*)d_in[3];
    const float* c = (const float*)d_in[4];
    const float* Wx = (const float*)d_in[5];
    const float* bx = (const float*)d_in[6];
    const float* Wh = (const float*)d_in[7];
    const float* bh = (const float*)d_in[8];
    const float* wc = (const float*)d_in[9];
    const float* bg = (const float*)d_in[10];
    const float* Whead = (const float*)d_in[11];
    const float* bhead = (const float*)d_in[12];

    int N = in_sizes[0] / IN_DIM;  // 50000
    int E = in_sizes[1] / 2;       // 800000
    const int* src = ei;
    const int* dst = ei + E;

    char* wp = (char*)d_ws;
    auto alloc = [&](size_t bytes) {
        char* p = wp;
        wp += (bytes + 255) & ~(size_t)255;
        return p;
    };
    float* deg = (float*)alloc((size_t)2 * N * 4);  // deg | cnt contiguous for memset
    int* cnt = (int*)(deg + N);
    int* rank_ = (int*)alloc((size_t)E * 4);
    int* rowptr = (int*)alloc((size_t)(N + 2) * 4);
    int* bsum = (int*)alloc(64 * 4);
    int2* eprm = (int2*)alloc((size_t)E * 8);
    ushort_t* xb = (ushort_t*)alloc((size_t)N * 128 * 2);
    ushort_t* hb = (ushort_t*)alloc((size_t)N * 64 * 2);
    ushort_t* Wp = (ushort_t*)alloc((size_t)384 * 256 * 2);

    hipMemsetAsync(deg, 0, (size_t)2 * N * sizeof(float), stream);

    int nScan = N + 1;
    int nChunk = (nScan + 1023) / 1024;   // 49

    prep_kernel<<<(E + 255) / 256, 256, 0, stream>>>(src, dst, ew, x, h, Wx, Wh,
                                                     deg, cnt, rank_,
                                                     (uint_t*)xb, (uint_t*)hb, Wp, E, N);
    scan1_kernel<<<nChunk, 256, 0, stream>>>(cnt, rowptr, bsum, nScan, N);
    fill_kernel<<<(E + 255) / 256, 256, 0, stream>>>(src, dst, ew, deg, rowptr, rank_,
                                                     bsum, nChunk, eprm, E);
    gather_mfma<<<(N + 63) / 64, 256, 0, stream>>>(rowptr, bsum, nChunk, eprm, xb, hb, c, Wp,
                                                   bx, bh, wc, bg, Whead, bhead,
                                                   (float*)d_out, N);
}